// Round 1
// baseline (617.218 us; speedup 1.0000x reference)
//
#include <hip/hip_runtime.h>

// ---------------------------------------------------------------------------
// Decoder: 6 conv_transpose3d layers (JAX SAME semantics, no kernel flip).
// Strategy: per layer, materialize a left/both-padded channels-last input
// P[z][y][x][ci], then tiled implicit-GEMM conv (M=64 spatial cube, N=64 cout,
// K = taps x ci-chunk) in fp32, atomicAdd for ci-split layers.
// Stride-2 layers decompose into 8 parity classes (per-dim taps: even ->
// {(t0,w0),(t1,w2)}, odd -> {(t1,w1)} on left-pad-1 input).
// ---------------------------------------------------------------------------

__global__ __launch_bounds__(256) void pad_x_k(const float* __restrict__ X,
                                               float* __restrict__ P) {
  int idx = blockIdx.x * 256 + threadIdx.x;   // P1: [5][5][5][1024]
  if (idx >= 125 * 1024) return;
  int c = idx & 1023;
  int r = idx >> 10;
  int px = r % 5, py = (r / 5) % 5, pz = r / 25;
  float v = 0.f;
  if (px >= 1 && py >= 1 && pz >= 1)
    v = X[c * 64 + (pz - 1) * 16 + (py - 1) * 4 + (px - 1)];  // NCDHW -> cl
  P[idx] = v;
}

template <int S, int PS, int C, int RELU>
__global__ __launch_bounds__(256) void pad_k(const float* __restrict__ I,
                                             float* __restrict__ P) {
  constexpr int TOT = PS * PS * PS * C;
  int idx = blockIdx.x * 256 + threadIdx.x;
  if (idx >= TOT) return;
  int c = idx % C;
  int r = idx / C;
  int px = r % PS;
  int ry = r / PS;
  int py = ry % PS, pz = ry / PS;
  int sx = px - 1, sy = py - 1, sz = pz - 1;
  float v = 0.f;
  if (sx >= 0 && sx < S && sy >= 0 && sy < S && sz >= 0 && sz < S) {
    v = I[(size_t)((sz * S + sy) * S + sx) * C + c];
    if (RELU) v = fmaxf(v, 0.f);
  }
  P[idx] = v;
}

// Tiled implicit-GEMM conv. M-tile = 4x4x4 output (u-space) cube, N-tile cout.
template <int CICHUNK, int CIN, int COUT, int NTILE, int STRIDE2, int SOUTU,
          int PS, int USE_ATOMIC>
__global__ __launch_bounds__(256) void conv_k(const float* __restrict__ P,
                                              const float* __restrict__ W,
                                              float* __restrict__ O) {
  constexpr int MT = SOUTU / 4;
  constexpr int MT3 = MT * MT * MT;
  constexpr int TX = NTILE / 4;     // threads along n
  constexpr int TY = 256 / TX;      // threads along m
  constexpr int MREP = 64 / TY;     // m per thread
  constexpr int EB = NTILE / 16;    // B-stage floats per thread
  constexpr int KB = 16;
  constexpr int S = STRIDE2 ? 2 * SOUTU : SOUTU;

  __shared__ __align__(16) float As[KB][64];
  __shared__ __align__(16) float Bs[KB][NTILE];

  int bx = blockIdx.x;
  int cls = 0;
  if (STRIDE2) { cls = bx / MT3; bx -= cls * MT3; }
  const int clz = (cls >> 2) & 1, cly = (cls >> 1) & 1, clx = cls & 1;
  const int u0z = (bx / (MT * MT)) * 4;
  const int u0y = ((bx / MT) % MT) * 4;
  const int u0x = (bx % MT) * 4;
  const int n_base = blockIdx.y * NTILE;
  const int ci_base = blockIdx.z * CICHUNK;

  const int t = threadIdx.x;
  // A staging: thread t loads As[ak][am..am+3] (4 x-consecutive positions)
  const int ak = t >> 4;
  const int am = (t & 15) * 4;
  const int amz = am >> 4, amy = (am >> 2) & 3;
  // B staging: thread t loads Bs[bk][bn..bn+EB-1]
  const int bk = t >> 4;
  const int bn = (t & 15) * EB;
  // compute mapping
  const int ctx = t % TX;
  const int cty = t / TX;
  const int n0 = ctx * 4;
  const int m0 = cty * MREP;

  float acc[MREP][4] = {};

  const int cz = STRIDE2 ? (clz ? 1 : 2) : 3;
  const int cy = STRIDE2 ? (cly ? 1 : 2) : 3;
  const int cx = STRIDE2 ? (clx ? 1 : 2) : 3;

  for (int iz = 0; iz < cz; iz++) {
    const int toz = STRIDE2 ? (clz ? 1 : iz) : iz;        // input pos offset
    const int wz  = STRIDE2 ? (clz ? 1 : 2 * iz) : iz;    // weight dz
    for (int iy = 0; iy < cy; iy++) {
      const int toy = STRIDE2 ? (cly ? 1 : iy) : iy;
      const int wy  = STRIDE2 ? (cly ? 1 : 2 * iy) : iy;
      for (int ix = 0; ix < cx; ix++) {
        const int tox = STRIDE2 ? (clx ? 1 : ix) : ix;
        const int wx  = STRIDE2 ? (clx ? 1 : 2 * ix) : ix;
        const float* Pb = P +
            (size_t)(((u0z + toz) * PS + (u0y + toy)) * PS + (u0x + tox)) * CIN +
            ci_base;
        const float* Wb = W +
            (size_t)(((wz * 3 + wy) * 3 + wx) * CIN + ci_base) * COUT + n_base;
        for (int kb = 0; kb < CICHUNK / KB; kb++) {
          {  // stage A (64 pos x 16 ci)
            const float* pa =
                Pb + (size_t)((amz * PS + amy) * PS) * CIN + kb * KB + ak;
            float a0 = pa[0], a1 = pa[CIN], a2 = pa[2 * CIN], a3 = pa[3 * CIN];
            *(float4*)&As[ak][am] = make_float4(a0, a1, a2, a3);
          }
          {  // stage B (16 ci x NTILE cout), weights already K x N row-major
            const float* pb = Wb + (size_t)(kb * KB + bk) * COUT + bn;
            if (EB == 4)
              *(float4*)&Bs[bk][bn] = *(const float4*)pb;
            else
              *(float2*)&Bs[bk][bn] = *(const float2*)pb;
          }
          __syncthreads();
#pragma unroll
          for (int k = 0; k < KB; k++) {
            float4 bv = *(const float4*)&Bs[k][n0];
#pragma unroll
            for (int j = 0; j < MREP; j++) {
              float av = As[k][m0 + j];
              acc[j][0] += av * bv.x;
              acc[j][1] += av * bv.y;
              acc[j][2] += av * bv.z;
              acc[j][3] += av * bv.w;
            }
          }
          __syncthreads();
        }
      }
    }
  }

#pragma unroll
  for (int j = 0; j < MREP; j++) {
    const int m = m0 + j;
    const int mz = m >> 4, my = (m >> 2) & 3, mx = m & 3;
    int oz, oy, ox;
    if (STRIDE2) {
      oz = 2 * (u0z + mz) + clz;
      oy = 2 * (u0y + my) + cly;
      ox = 2 * (u0x + mx) + clx;
    } else {
      oz = u0z + mz;
      oy = u0y + my;
      ox = u0x + mx;
    }
    float* o = O + (size_t)((oz * S + oy) * S + ox) * COUT + n_base + n0;
    if (USE_ATOMIC) {
      atomicAdd(o + 0, acc[j][0]);
      atomicAdd(o + 1, acc[j][1]);
      atomicAdd(o + 2, acc[j][2]);
      atomicAdd(o + 3, acc[j][3]);
    } else {
      *(float4*)o = make_float4(acc[j][0], acc[j][1], acc[j][2], acc[j][3]);
    }
  }
}

// Layer 6: 32 -> 1 channels, direct per-output dot product (GEMV-shaped).
__global__ __launch_bounds__(256) void conv6_k(const float* __restrict__ P,
                                               const float* __restrict__ W6,
                                               float* __restrict__ O) {
  __shared__ __align__(16) float w[864];  // 27*32
  for (int i = threadIdx.x; i < 864; i += 256) w[i] = W6[i];
  __syncthreads();
  int idx = blockIdx.x * 256 + threadIdx.x;  // 32768 outputs
  int x = idx & 31, y = (idx >> 5) & 31, z = idx >> 10;
  float4 a = make_float4(0.f, 0.f, 0.f, 0.f);
  for (int dz = 0; dz < 3; dz++)
    for (int dy = 0; dy < 3; dy++)
      for (int dx = 0; dx < 3; dx++) {
        const float* p =
            P + (size_t)(((z + dz) * 34 + (y + dy)) * 34 + (x + dx)) * 32;
        const float* ww = &w[((dz * 3 + dy) * 3 + dx) * 32];
#pragma unroll
        for (int c = 0; c < 32; c += 4) {
          float4 pv = *(const float4*)&p[c];
          float4 wv = *(const float4*)&ww[c];
          a.x += pv.x * wv.x;
          a.y += pv.y * wv.y;
          a.z += pv.z * wv.z;
          a.w += pv.w * wv.w;
        }
      }
  O[idx] = a.x + a.y + a.z + a.w;
}

extern "C" void kernel_launch(void* const* d_in, const int* in_sizes, int n_in,
                              void* d_out, int out_size, void* d_ws,
                              size_t ws_size, hipStream_t stream) {
  const float* x  = (const float*)d_in[0];
  const float* w1 = (const float*)d_in[1];
  const float* w2 = (const float*)d_in[2];
  const float* w3 = (const float*)d_in[3];
  const float* w4 = (const float*)d_in[4];
  const float* w5 = (const float*)d_in[5];
  const float* w6 = (const float*)d_in[6];
  float* out = (float*)d_out;
  float* ws = (float*)d_ws;

  // workspace layout (floats); O1..O4 contiguous for one memset
  const size_t oP1 = 0;                       // 5^3 *1024 = 128000
  const size_t oO1 = oP1 + 125 * 1024;        // 8^3 *512  = 262144
  const size_t oO2 = oO1 + 512 * 512;         // 8^3 *256  = 131072
  const size_t oO3 = oO2 + 512 * 256;         // 16^3*128  = 524288
  const size_t oO4 = oO3 + 4096 * 128;        // 16^3*64   = 262144
  const size_t oP2 = oO4 + 4096 * 64;         // 10^3*512  = 512000
  const size_t oP3 = oP2 + 1000 * 512;        // 9^3 *256  = 186624
  const size_t oP4 = oP3 + 729 * 256;         // 18^3*128  = 746496
  const size_t oP5 = oP4 + 5832 * 128;        // 17^3*64   = 314432
  const size_t oO5 = oP5 + 4913 * 64;         // 32^3*32   = 1048576
  const size_t oP6 = oO5 + 32768 * 32;        // 34^3*32   = 1257728
  // total ~21.5 MB

  hipMemsetAsync(ws + oO1, 0, (oP2 - oO1) * sizeof(float), stream);

  // L1: 1024->512, 4^3 -> 8^3, stride 2
  pad_x_k<<<500, 256, 0, stream>>>(x, ws + oP1);
  conv_k<128, 1024, 512, 64, 1, 4, 5, 1>
      <<<dim3(8, 8, 8), 256, 0, stream>>>(ws + oP1, w1, ws + oO1);
  // L2: 512->256, 8^3, stride 1
  pad_k<8, 10, 512, 1><<<2000, 256, 0, stream>>>(ws + oO1, ws + oP2);
  conv_k<64, 512, 256, 64, 0, 8, 10, 1>
      <<<dim3(8, 4, 8), 256, 0, stream>>>(ws + oP2, w2, ws + oO2);
  // L3: 256->128, 8^3 -> 16^3, stride 2
  pad_k<8, 9, 256, 1><<<729, 256, 0, stream>>>(ws + oO2, ws + oP3);
  conv_k<128, 256, 128, 64, 1, 8, 9, 1>
      <<<dim3(64, 2, 2), 256, 0, stream>>>(ws + oP3, w3, ws + oO3);
  // L4: 128->64, 16^3, stride 1
  pad_k<16, 18, 128, 1><<<2916, 256, 0, stream>>>(ws + oO3, ws + oP4);
  conv_k<32, 128, 64, 64, 0, 16, 18, 1>
      <<<dim3(64, 1, 4), 256, 0, stream>>>(ws + oP4, w4, ws + oO4);
  // L5: 64->32, 16^3 -> 32^3, stride 2
  pad_k<16, 17, 64, 1><<<1229, 256, 0, stream>>>(ws + oO4, ws + oP5);
  conv_k<64, 64, 32, 32, 1, 16, 17, 0>
      <<<dim3(512, 1, 1), 256, 0, stream>>>(ws + oP5, w5, ws + oO5);
  // L6: 32->1, 32^3, stride 1, no relu
  pad_k<32, 34, 32, 1><<<4913, 256, 0, stream>>>(ws + oO5, ws + oP6);
  conv6_k<<<128, 256, 0, stream>>>(ws + oP6, w6, out);

  (void)in_sizes; (void)n_in; (void)out_size; (void)ws_size;
}

// Round 2
// 238.233 us; speedup vs baseline: 2.5908x; 2.5908x over previous
//
#include <hip/hip_runtime.h>

typedef _Float16 half8 __attribute__((ext_vector_type(8)));
typedef _Float16 half4v __attribute__((ext_vector_type(4)));
typedef float floatx4 __attribute__((ext_vector_type(4)));

// ---------------------------------------------------------------------------
// Decoder: 6 conv_transpose3d (JAX SAME, no kernel flip), fp16 MFMA version.
// Per layer: pad (+ReLU + fp32->fp16) to channels-last P[z][y][x][ci], then
// implicit-GEMM conv with mfma_f32_16x16x32_f16, fp32 accumulate, atomic or
// direct fp32 store. Stride-2 layers decompose into 8 parity classes.
// Weights are transposed+converted once per call to Wt[tap][cout][cin] fp16.
// ---------------------------------------------------------------------------

__global__ __launch_bounds__(256) void pad_x_k(const float* __restrict__ X,
                                               _Float16* __restrict__ P) {
  int idx = blockIdx.x * 256 + threadIdx.x;   // P1: [5][5][5][1024]
  if (idx >= 125 * 1024) return;
  int c = idx & 1023;
  int r = idx >> 10;
  int px = r % 5, py = (r / 5) % 5, pz = r / 25;
  float v = 0.f;
  if (px >= 1 && py >= 1 && pz >= 1)
    v = X[c * 64 + (pz - 1) * 16 + (py - 1) * 4 + (px - 1)];  // NCDHW -> cl
  P[idx] = (_Float16)v;
}

template <int S, int PS, int C, int RELU>
__global__ __launch_bounds__(256) void pad_k(const float* __restrict__ I,
                                             _Float16* __restrict__ P) {
  constexpr int TOT = PS * PS * PS * C;
  int idx = blockIdx.x * 256 + threadIdx.x;
  if (idx >= TOT) return;
  int c = idx % C;
  int r = idx / C;
  int px = r % PS;
  int ry = r / PS;
  int py = ry % PS, pz = ry / PS;
  int sx = px - 1, sy = py - 1, sz = pz - 1;
  float v = 0.f;
  if (sx >= 0 && sx < S && sy >= 0 && sy < S && sz >= 0 && sz < S) {
    v = I[(size_t)((sz * S + sy) * S + sx) * C + c];
    if (RELU) v = fmaxf(v, 0.f);
  }
  P[idx] = (_Float16)v;
}

// Weight transform: W[tap][cin][cout] fp32 -> Wt[tap][cout][cin] fp16,
// 32x32 LDS-tiled transpose. One dispatch covers all 5 MFMA layers.
__global__ __launch_bounds__(256) void wt_k(
    const float* __restrict__ w1, const float* __restrict__ w2,
    const float* __restrict__ w3, const float* __restrict__ w4,
    const float* __restrict__ w5, _Float16* __restrict__ t1,
    _Float16* __restrict__ t2, _Float16* __restrict__ t3,
    _Float16* __restrict__ t4, _Float16* __restrict__ t5) {
  int b = blockIdx.x;
  const float* W;
  _Float16* T;
  int cin, cout;
  if (b < 13824)      { W = w1; T = t1; cin = 1024; cout = 512; }
  else if (b < 17280) { b -= 13824; W = w2; T = t2; cin = 512; cout = 256; }
  else if (b < 18144) { b -= 17280; W = w3; T = t3; cin = 256; cout = 128; }
  else if (b < 18360) { b -= 18144; W = w4; T = t4; cin = 128; cout = 64; }
  else                { b -= 18360; W = w5; T = t5; cin = 64;  cout = 32; }
  const int citiles = cin >> 5;
  const int per_tap = (cout >> 5) * citiles;
  const int tap = b / per_tap;
  const int r = b - tap * per_tap;
  const int cot = r / citiles, cit = r - cot * citiles;

  __shared__ float tile[32][33];
  const int t = threadIdx.x;
  const int rr = t >> 3, c4 = (t & 7) * 4;
  const float* src =
      W + ((size_t)(tap * cin + cit * 32 + rr)) * cout + cot * 32 + c4;
  float4 v = *(const float4*)src;
  tile[rr][c4] = v.x; tile[rr][c4 + 1] = v.y;
  tile[rr][c4 + 2] = v.z; tile[rr][c4 + 3] = v.w;
  __syncthreads();
  half4v h;
  h[0] = (_Float16)tile[c4 + 0][rr];
  h[1] = (_Float16)tile[c4 + 1][rr];
  h[2] = (_Float16)tile[c4 + 2][rr];
  h[3] = (_Float16)tile[c4 + 3][rr];
  *(half4v*)(T + ((size_t)(tap * cout + cot * 32 + rr)) * cin + cit * 32 + c4) = h;
}

// MFMA implicit-GEMM conv. Block = 256 threads = 4 waves.
// NTILE==64: waves 2m x 2n, block tile M=64 x N=64 (u-tile 4x4x4).
// NTILE==32: waves 4m x 1n, block tile M=128 x N=32 (u-tile 8x4x4).
template <int CICHUNK, int CIN, int COUT, int NTILE, int STRIDE2, int SOUTU,
          int TZ, int PS, int USE_ATOMIC>
__global__ __launch_bounds__(256) void conv_mfma_k(
    const _Float16* __restrict__ P, const _Float16* __restrict__ Wt,
    float* __restrict__ O) {
  constexpr int M = TZ * 16;               // 64 or 128
  constexpr int MTZ = SOUTU / TZ;
  constexpr int MTXY = SOUTU / 4;
  constexpr int MT3 = MTZ * MTXY * MTXY;
  constexpr int KB = 32;
  constexpr int KP = KB + 8;               // padded LDS row (halves)
  constexpr int S = STRIDE2 ? 2 * SOUTU : SOUTU;

  __shared__ __align__(16) _Float16 As[M][KP];
  __shared__ __align__(16) _Float16 Bs[NTILE][KP];

  int bx = blockIdx.x;
  int cls = 0;
  if (STRIDE2) { cls = bx / MT3; bx -= cls * MT3; }
  const int clz = (cls >> 2) & 1, cly = (cls >> 1) & 1, clx = cls & 1;
  const int u0z = (bx / (MTXY * MTXY)) * TZ;
  const int u0y = ((bx / MTXY) % MTXY) * 4;
  const int u0x = (bx % MTXY) * 4;
  const int n_base = blockIdx.y * NTILE;
  const int ci_base = blockIdx.z * CICHUNK;

  const int t = threadIdx.x;
  const int lane = t & 63;
  const int wave = t >> 6;

  // staging mapping: lane-groups of 4 cover k (4 x 8 halves = 32)
  const int skq = t & 3;
  const int sp = t >> 2;                   // 0..63: A pos (and +64), B n-row
  const int spx = sp & 3, spy = (sp >> 2) & 3, spz = sp >> 4;
  const int aoff0 = ((spz * PS + spy) * PS + spx) * CIN;
  const int aoff1 = (((spz + 4) * PS + spy) * PS + spx) * CIN;  // M==128 only

  // compute mapping
  const int m0w = (NTILE == 64) ? (wave >> 1) * 32 : wave * 32;
  const int n0w = (NTILE == 64) ? (wave & 1) * 32 : 0;
  const int fr = lane & 15;
  const int fq = lane >> 4;

  floatx4 acc[2][2];
#pragma unroll
  for (int i = 0; i < 2; i++)
#pragma unroll
    for (int j = 0; j < 2; j++) acc[i][j] = {0.f, 0.f, 0.f, 0.f};

  const int cz = STRIDE2 ? (clz ? 1 : 2) : 3;
  const int cy = STRIDE2 ? (cly ? 1 : 2) : 3;
  const int cx = STRIDE2 ? (clx ? 1 : 2) : 3;

  for (int iz = 0; iz < cz; iz++) {
    const int toz = STRIDE2 ? (clz ? 1 : iz) : iz;
    const int wz  = STRIDE2 ? (clz ? 1 : 2 * iz) : iz;
    for (int iy = 0; iy < cy; iy++) {
      const int toy = STRIDE2 ? (cly ? 1 : iy) : iy;
      const int wy  = STRIDE2 ? (cly ? 1 : 2 * iy) : iy;
      for (int ix = 0; ix < cx; ix++) {
        const int tox = STRIDE2 ? (clx ? 1 : ix) : ix;
        const int wx  = STRIDE2 ? (clx ? 1 : 2 * ix) : ix;
        const _Float16* Pb = P +
            (size_t)(((u0z + toz) * PS + (u0y + toy)) * PS + (u0x + tox)) * CIN +
            ci_base;
        const _Float16* Wb = Wt +
            ((size_t)((wz * 3 + wy) * 3 + wx) * COUT + n_base) * CIN + ci_base;
        for (int kb = 0; kb < CICHUNK / KB; kb++) {
          const int ko = kb * KB + skq * 8;
          *(half8*)&As[sp][skq * 8] = *(const half8*)(Pb + aoff0 + ko);
          if (M == 128)
            *(half8*)&As[sp + 64][skq * 8] = *(const half8*)(Pb + aoff1 + ko);
          if (NTILE == 64 || sp < NTILE)
            *(half8*)&Bs[sp][skq * 8] =
                *(const half8*)(Wb + (size_t)sp * CIN + ko);
          __syncthreads();
          half8 a0 = *(const half8*)&As[m0w + fr][fq * 8];
          half8 a1 = *(const half8*)&As[m0w + 16 + fr][fq * 8];
          half8 b0 = *(const half8*)&Bs[n0w + fr][fq * 8];
          half8 b1 = *(const half8*)&Bs[n0w + 16 + fr][fq * 8];
          acc[0][0] = __builtin_amdgcn_mfma_f32_16x16x32_f16(a0, b0, acc[0][0], 0, 0, 0);
          acc[0][1] = __builtin_amdgcn_mfma_f32_16x16x32_f16(a0, b1, acc[0][1], 0, 0, 0);
          acc[1][0] = __builtin_amdgcn_mfma_f32_16x16x32_f16(a1, b0, acc[1][0], 0, 0, 0);
          acc[1][1] = __builtin_amdgcn_mfma_f32_16x16x32_f16(a1, b1, acc[1][1], 0, 0, 0);
          __syncthreads();
        }
      }
    }
  }

#pragma unroll
  for (int i = 0; i < 2; i++) {
#pragma unroll
    for (int r = 0; r < 4; r++) {
      const int m = m0w + i * 16 + fq * 4 + r;
      const int mz = m >> 4, my = (m >> 2) & 3, mx = m & 3;
      int oz, oy, ox;
      if (STRIDE2) {
        oz = 2 * (u0z + mz) + clz;
        oy = 2 * (u0y + my) + cly;
        ox = 2 * (u0x + mx) + clx;
      } else {
        oz = u0z + mz;
        oy = u0y + my;
        ox = u0x + mx;
      }
      float* obase = O + (size_t)((oz * S + oy) * S + ox) * COUT + n_base + n0w;
#pragma unroll
      for (int j = 0; j < 2; j++) {
        float* o = obase + j * 16 + fr;
        if (USE_ATOMIC) atomicAdd(o, acc[i][j][r]);
        else *o = acc[i][j][r];
      }
    }
  }
}

// Layer 6: 32 -> 1 channels, per-output dot product.
__global__ __launch_bounds__(256) void conv6_k(const _Float16* __restrict__ P,
                                               const float* __restrict__ W6,
                                               float* __restrict__ O) {
  __shared__ __align__(16) float w[864];  // 27*32
  for (int i = threadIdx.x; i < 864; i += 256) w[i] = W6[i];
  __syncthreads();
  int idx = blockIdx.x * 256 + threadIdx.x;  // 32768 outputs
  int x = idx & 31, y = (idx >> 5) & 31, z = idx >> 10;
  float a = 0.f;
  for (int dz = 0; dz < 3; dz++)
    for (int dy = 0; dy < 3; dy++)
      for (int dx = 0; dx < 3; dx++) {
        const _Float16* p =
            P + (size_t)(((z + dz) * 34 + (y + dy)) * 34 + (x + dx)) * 32;
        const float* ww = &w[((dz * 3 + dy) * 3 + dx) * 32];
#pragma unroll
        for (int c = 0; c < 32; c += 8) {
          half8 pv = *(const half8*)&p[c];
#pragma unroll
          for (int u = 0; u < 8; u++) a += (float)pv[u] * ww[c + u];
        }
      }
  O[idx] = a;
}

extern "C" void kernel_launch(void* const* d_in, const int* in_sizes, int n_in,
                              void* d_out, int out_size, void* d_ws,
                              size_t ws_size, hipStream_t stream) {
  const float* x  = (const float*)d_in[0];
  const float* w1 = (const float*)d_in[1];
  const float* w2 = (const float*)d_in[2];
  const float* w3 = (const float*)d_in[3];
  const float* w4 = (const float*)d_in[4];
  const float* w5 = (const float*)d_in[5];
  const float* w6 = (const float*)d_in[6];
  float* out = (float*)d_out;

  // fp32 region
  float* O1 = (float*)d_ws;            // 8^3 *512  = 262144
  float* O2 = O1 + 262144;             // 8^3 *256  = 131072
  float* O3 = O2 + 131072;             // 16^3*128  = 524288
  float* O4 = O3 + 524288;             // 16^3*64   = 262144
  float* O5 = O4 + 262144;             // 32^3*32   = 1048576
  // fp16 region
  _Float16* P1 = (_Float16*)(O5 + 1048576);  // 5^3 *1024 = 128000
  _Float16* P2 = P1 + 128000;          // 10^3*512 = 512000
  _Float16* P3 = P2 + 512000;          // 9^3 *256 = 186624
  _Float16* P4 = P3 + 186624;          // 18^3*128 = 746496
  _Float16* P5 = P4 + 746496;          // 17^3*64  = 314432
  _Float16* P6 = P5 + 314432;          // 34^3*32  = 1257728
  _Float16* T1 = P6 + 1257728;         // 27*512*1024 = 14155776
  _Float16* T2 = T1 + 14155776;        // 27*256*512  = 3538944
  _Float16* T3 = T2 + 3538944;         // 27*128*256  = 884736
  _Float16* T4 = T3 + 884736;          // 27*64*128   = 221184
  _Float16* T5 = T4 + 221184;          // 27*32*64    = 55296

  // weight transform (all 5 MFMA layers, one dispatch)
  wt_k<<<18414, 256, 0, stream>>>(w1, w2, w3, w4, w5, T1, T2, T3, T4, T5);
  // zero atomic destinations O1..O4 (contiguous)
  hipMemsetAsync(O1, 0, (262144 + 131072 + 524288 + 262144) * sizeof(float),
                 stream);

  // L1: 1024->512, 4^3 -> 8^3, s2
  pad_x_k<<<500, 256, 0, stream>>>(x, P1);
  conv_mfma_k<256, 1024, 512, 64, 1, 4, 4, 5, 1>
      <<<dim3(8, 8, 4), 256, 0, stream>>>(P1, T1, O1);
  // L2: 512->256, 8^3, s1
  pad_k<8, 10, 512, 1><<<2000, 256, 0, stream>>>(O1, P2);
  conv_mfma_k<64, 512, 256, 64, 0, 8, 4, 10, 1>
      <<<dim3(8, 4, 8), 256, 0, stream>>>(P2, T2, O2);
  // L3: 256->128, 8^3 -> 16^3, s2
  pad_k<8, 9, 256, 1><<<729, 256, 0, stream>>>(O2, P3);
  conv_mfma_k<128, 256, 128, 64, 1, 8, 4, 9, 1>
      <<<dim3(64, 2, 2), 256, 0, stream>>>(P3, T3, O3);
  // L4: 128->64, 16^3, s1
  pad_k<16, 18, 128, 1><<<2916, 256, 0, stream>>>(O3, P4);
  conv_mfma_k<32, 128, 64, 64, 0, 16, 4, 18, 1>
      <<<dim3(64, 1, 4), 256, 0, stream>>>(P4, T4, O4);
  // L5: 64->32, 16^3 -> 32^3, s2 (no ci split -> direct store)
  pad_k<16, 17, 64, 1><<<1229, 256, 0, stream>>>(O4, P5);
  conv_mfma_k<64, 64, 32, 32, 1, 16, 8, 17, 0>
      <<<dim3(256, 1, 1), 256, 0, stream>>>(P5, T5, O5);
  // L6: 32->1, 32^3, s1, no final ReLU
  pad_k<32, 34, 32, 1><<<4913, 256, 0, stream>>>(O5, P6);
  conv6_k<<<128, 256, 0, stream>>>(P6, w6, out);

  (void)in_sizes; (void)n_in; (void)out_size; (void)ws_size;
}

// Round 3
// 216.091 us; speedup vs baseline: 2.8563x; 1.1025x over previous
//
#include <hip/hip_runtime.h>

typedef _Float16 half8 __attribute__((ext_vector_type(8)));
typedef _Float16 half4v __attribute__((ext_vector_type(4)));
typedef float floatx4 __attribute__((ext_vector_type(4)));

// ---------------------------------------------------------------------------
// Decoder: 6 conv_transpose3d (JAX SAME, no kernel flip), fp16 MFMA.
// Per layer: pad (+ReLU + fp32->fp16) to channels-last P[z][y][x][ci], then
// implicit-GEMM conv with mfma_f32_16x16x32_f16, fp32 accumulate.
// Weights are read directly as fp32 [tap][cin][cout] and transposed+converted
// into the LDS B-tile during staging (no separate transform kernel).
// Stride-2 layers decompose into 8 parity classes. Linearized (tap x kb) loop
// with register prefetch of the next iteration's global loads.
// ---------------------------------------------------------------------------

__global__ __launch_bounds__(256) void pad_x_k(const float* __restrict__ X,
                                               _Float16* __restrict__ P) {
  int idx = blockIdx.x * 256 + threadIdx.x;   // P1: [5][5][5][1024]
  if (idx >= 125 * 1024) return;
  int c = idx & 1023;
  int r = idx >> 10;
  int px = r % 5, py = (r / 5) % 5, pz = r / 25;
  float v = 0.f;
  if (px >= 1 && py >= 1 && pz >= 1)
    v = X[c * 64 + (pz - 1) * 16 + (py - 1) * 4 + (px - 1)];  // NCDHW -> cl
  P[idx] = (_Float16)v;
}

template <int S, int PS, int C, int RELU>
__global__ __launch_bounds__(256) void pad_k(const float* __restrict__ I,
                                             _Float16* __restrict__ P) {
  constexpr int TOT = PS * PS * PS * C;
  int idx = blockIdx.x * 256 + threadIdx.x;
  if (idx >= TOT) return;
  int c = idx % C;
  int r = idx / C;
  int px = r % PS;
  int ry = r / PS;
  int py = ry % PS, pz = ry / PS;
  int sx = px - 1, sy = py - 1, sz = pz - 1;
  float v = 0.f;
  if (sx >= 0 && sx < S && sy >= 0 && sy < S && sz >= 0 && sz < S) {
    v = I[(size_t)((sz * S + sy) * S + sx) * C + c];
    if (RELU) v = fmaxf(v, 0.f);
  }
  P[idx] = (_Float16)v;
}

// MFMA implicit-GEMM conv. Block = 256 threads = 4 waves.
// NTILE==64: waves 2m x 2n, tile M=64 x N=64 (u-tile 4x4x4, TZ=4).
// NTILE==32: waves 4m x 1n, tile M=128 x N=32 (u-tile 8x4x4, TZ=8).
// STORE_MODE: 0 = fp32 store, 1 = fp32 atomicAdd, 2 = fp16 ReLU store into
// padded (S+2)^3 channels-last buffer.
template <int CICHUNK, int CIN, int COUT, int NTILE, int STRIDE2, int SOUTU,
          int TZ, int PS, int STORE_MODE>
__global__ __launch_bounds__(256) void conv_mfma_k(
    const _Float16* __restrict__ P, const float* __restrict__ W,
    void* __restrict__ Optr) {
  constexpr int M = TZ * 16;               // 64 or 128
  constexpr int MTZ = SOUTU / TZ;
  constexpr int MTXY = SOUTU / 4;
  constexpr int MT3 = MTZ * MTXY * MTXY;
  constexpr int KB = 32;
  constexpr int KP = 40;                   // padded LDS row (halves)
  constexpr int KBI = CICHUNK / KB;
  constexpr int S = STRIDE2 ? 2 * SOUTU : SOUTU;
  constexpr int BJ = (NTILE == 64) ? 8 : 4;  // B fp32 values per thread

  __shared__ __align__(16) _Float16 As[M][KP];
  __shared__ __align__(16) _Float16 Bs[NTILE][KP];

  int bx = blockIdx.x;
  int cls = 0;
  if (STRIDE2) { cls = bx / MT3; bx -= cls * MT3; }
  const int clz = (cls >> 2) & 1, cly = (cls >> 1) & 1, clx = cls & 1;
  const int u0z = (bx / (MTXY * MTXY)) * TZ;
  const int u0y = ((bx / MTXY) % MTXY) * 4;
  const int u0x = (bx % MTXY) * 4;
  const int n_base = blockIdx.y * NTILE;
  const int ci_base = blockIdx.z * CICHUNK;

  const int t = threadIdx.x;
  const int lane = t & 63;
  const int wave = t >> 6;

  // A staging: thread t loads 8 halves for position sp, k-chunk skq
  const int skq = t & 3;
  const int sp = t >> 2;                   // 0..63
  const int spx = sp & 3, spy = (sp >> 2) & 3, spz = sp >> 4;
  const int aoffsp = ((spz * PS + spy) * PS + spx) * CIN + skq * 8;
  const int aoffsp2 = (((spz + 4) * PS + spy) * PS + spx) * CIN + skq * 8;

  // B staging: thread t covers n=nB, k = k0B..k0B+BJ-1 (transpose+convert)
  const int nB = t & (NTILE - 1);
  const int k0B = (t / NTILE) * BJ;

  // compute mapping
  const int m0w = (NTILE == 64) ? (wave >> 1) * 32 : wave * 32;
  const int n0w = (NTILE == 64) ? (wave & 1) * 32 : 0;
  const int fr = lane & 15;
  const int fq = lane >> 4;

  const int cz = STRIDE2 ? (clz ? 1 : 2) : 3;
  const int cy = STRIDE2 ? (cly ? 1 : 2) : 3;
  const int cx = STRIDE2 ? (clx ? 1 : 2) : 3;
  const int ctaps = cz * cy * cx;
  const int NIT = ctaps * KBI;
  const int shx = STRIDE2 ? (clx ? 0 : 1) : 0;
  const int shy = STRIDE2 ? (cly ? 0 : 1) : 0;

  floatx4 acc[2][2];
#pragma unroll
  for (int i = 0; i < 2; i++)
#pragma unroll
    for (int j = 0; j < 2; j++) acc[i][j] = {0.f, 0.f, 0.f, 0.f};

  half8 raA = {}, raB = {}, raA2 = {}, raB2 = {};
  float bwv[BJ] = {}, bwv2[BJ] = {};

  auto load_it = [&](int it, half8& A0, half8& A1, float* BW) {
    int tap, kb;
    if (KBI == 1) { tap = it; kb = 0; }
    else { tap = it / KBI; kb = it - tap * KBI; }
    int iz, iy, ix;
    if (STRIDE2) {
      const int shyx = shx + shy;
      iz = tap >> shyx;
      int rem = tap - (iz << shyx);
      iy = rem >> shx;
      ix = rem - (iy << shx);
    } else {
      iz = tap / 9;
      int rem = tap - iz * 9;
      iy = rem / 3;
      ix = rem - iy * 3;
    }
    const int toz = STRIDE2 ? (clz ? 1 : iz) : iz;
    const int wz  = STRIDE2 ? (clz ? 1 : 2 * iz) : iz;
    const int toy = STRIDE2 ? (cly ? 1 : iy) : iy;
    const int wy  = STRIDE2 ? (cly ? 1 : 2 * iy) : iy;
    const int tox = STRIDE2 ? (clx ? 1 : ix) : ix;
    const int wx  = STRIDE2 ? (clx ? 1 : 2 * ix) : ix;
    const int kofs = ci_base + kb * KB;
    const size_t pbase =
        (size_t)(((u0z + toz) * PS + (u0y + toy)) * PS + (u0x + tox)) * CIN +
        kofs;
    A0 = *(const half8*)(P + pbase + aoffsp);
    if (M == 128) A1 = *(const half8*)(P + pbase + aoffsp2);
    const int wtap = (wz * 3 + wy) * 3 + wx;
    const float* wb =
        W + ((size_t)wtap * CIN + kofs + k0B) * COUT + n_base + nB;
#pragma unroll
    for (int j = 0; j < BJ; j++) BW[j] = wb[(size_t)j * COUT];
  };

  load_it(0, raA, raB, bwv);

  for (int it = 0; it < NIT; ++it) {
    // stage current registers -> LDS
    *(half8*)&As[sp][skq * 8] = raA;
    if (M == 128) *(half8*)&As[sp + 64][skq * 8] = raB;
    {
      half4v h0;
#pragma unroll
      for (int j = 0; j < 4; j++) h0[j] = (_Float16)bwv[j];
      *(half4v*)&Bs[nB][k0B] = h0;
      if (BJ == 8) {
        half4v h1;
#pragma unroll
        for (int j = 0; j < 4; j++) h1[j] = (_Float16)bwv[4 + j];
        *(half4v*)&Bs[nB][k0B + 4] = h1;
      }
    }
    __syncthreads();
    if (it + 1 < NIT) load_it(it + 1, raA2, raB2, bwv2);
    half8 a0 = *(const half8*)&As[m0w + fr][fq * 8];
    half8 a1 = *(const half8*)&As[m0w + 16 + fr][fq * 8];
    half8 b0 = *(const half8*)&Bs[n0w + fr][fq * 8];
    half8 b1 = *(const half8*)&Bs[n0w + 16 + fr][fq * 8];
    acc[0][0] = __builtin_amdgcn_mfma_f32_16x16x32_f16(a0, b0, acc[0][0], 0, 0, 0);
    acc[0][1] = __builtin_amdgcn_mfma_f32_16x16x32_f16(a0, b1, acc[0][1], 0, 0, 0);
    acc[1][0] = __builtin_amdgcn_mfma_f32_16x16x32_f16(a1, b0, acc[1][0], 0, 0, 0);
    acc[1][1] = __builtin_amdgcn_mfma_f32_16x16x32_f16(a1, b1, acc[1][1], 0, 0, 0);
    __syncthreads();
    raA = raA2;
    raB = raB2;
#pragma unroll
    for (int j = 0; j < BJ; j++) bwv[j] = bwv2[j];
  }

#pragma unroll
  for (int i = 0; i < 2; i++) {
#pragma unroll
    for (int r = 0; r < 4; r++) {
      const int m = m0w + i * 16 + fq * 4 + r;
      const int mz = m >> 4, my = (m >> 2) & 3, mx = m & 3;
      int oz, oy, ox;
      if (STRIDE2) {
        oz = 2 * (u0z + mz) + clz;
        oy = 2 * (u0y + my) + cly;
        ox = 2 * (u0x + mx) + clx;
      } else {
        oz = u0z + mz;
        oy = u0y + my;
        ox = u0x + mx;
      }
      if (STORE_MODE == 2) {
        _Float16* o = (_Float16*)Optr +
            (size_t)(((oz + 1) * (S + 2) + (oy + 1)) * (S + 2) + (ox + 1)) *
                COUT + n_base + n0w;
#pragma unroll
        for (int j = 0; j < 2; j++)
          o[j * 16 + fr] = (_Float16)fmaxf(acc[i][j][r], 0.f);
      } else {
        float* o = (float*)Optr +
            (size_t)((oz * S + oy) * S + ox) * COUT + n_base + n0w;
#pragma unroll
        for (int j = 0; j < 2; j++) {
          if (STORE_MODE == 1) atomicAdd(o + j * 16 + fr, acc[i][j][r]);
          else o[j * 16 + fr] = acc[i][j][r];
        }
      }
    }
  }
}

// Layer 6: 32 -> 1 channels, per-output dot product.
__global__ __launch_bounds__(256) void conv6_k(const _Float16* __restrict__ P,
                                               const float* __restrict__ W6,
                                               float* __restrict__ O) {
  __shared__ __align__(16) float w[864];  // 27*32
  for (int i = threadIdx.x; i < 864; i += 256) w[i] = W6[i];
  __syncthreads();
  int idx = blockIdx.x * 256 + threadIdx.x;  // 32768 outputs
  int x = idx & 31, y = (idx >> 5) & 31, z = idx >> 10;
  float a = 0.f;
  for (int dz = 0; dz < 3; dz++)
    for (int dy = 0; dy < 3; dy++)
      for (int dx = 0; dx < 3; dx++) {
        const _Float16* p =
            P + (size_t)(((z + dz) * 34 + (y + dy)) * 34 + (x + dx)) * 32;
        const float* ww = &w[((dz * 3 + dy) * 3 + dx) * 32];
#pragma unroll
        for (int c = 0; c < 32; c += 8) {
          half8 pv = *(const half8*)&p[c];
#pragma unroll
          for (int u = 0; u < 8; u++) a += (float)pv[u] * ww[c + u];
        }
      }
  O[idx] = a;
}

extern "C" void kernel_launch(void* const* d_in, const int* in_sizes, int n_in,
                              void* d_out, int out_size, void* d_ws,
                              size_t ws_size, hipStream_t stream) {
  const float* x  = (const float*)d_in[0];
  const float* w1 = (const float*)d_in[1];
  const float* w2 = (const float*)d_in[2];
  const float* w3 = (const float*)d_in[3];
  const float* w4 = (const float*)d_in[4];
  const float* w5 = (const float*)d_in[5];
  const float* w6 = (const float*)d_in[6];
  float* out = (float*)d_out;

  // fp32 atomic destinations (must be zeroed), then P6, then fp16 pads
  float* O1 = (float*)d_ws;                  // 8^3 *512  = 262144
  float* O2 = O1 + 262144;                   // 8^3 *256  = 131072
  float* O3 = O2 + 131072;                   // 16^3*128  = 524288
  float* O4 = O3 + 524288;                   // 16^3*64   = 262144
  _Float16* P6 = (_Float16*)(O4 + 262144);   // 34^3*32   = 1257728 (zeroed)
  _Float16* P1 = P6 + 1257728;               // 5^3 *1024 = 128000
  _Float16* P2 = P1 + 128000;                // 10^3*512  = 512000
  _Float16* P3 = P2 + 512000;                // 9^3 *256  = 186624
  _Float16* P4 = P3 + 186624;                // 18^3*128  = 746496
  _Float16* P5 = P4 + 746496;                // 17^3*64   = 314432

  // zero O1..O4 (fp32 atomics) + P6 (direct fp16 store w/ pad border)
  hipMemsetAsync(d_ws, 0, 1179648 * sizeof(float) + 1257728 * sizeof(_Float16),
                 stream);

  // L1: 1024->512, 4^3 -> 8^3, s2
  pad_x_k<<<500, 256, 0, stream>>>(x, P1);
  conv_mfma_k<128, 1024, 512, 64, 1, 4, 4, 5, 1>
      <<<dim3(8, 8, 8), 256, 0, stream>>>(P1, w1, O1);
  // L2: 512->256, 8^3, s1
  pad_k<8, 10, 512, 1><<<2000, 256, 0, stream>>>(O1, P2);
  conv_mfma_k<32, 512, 256, 64, 0, 8, 4, 10, 1>
      <<<dim3(8, 4, 16), 256, 0, stream>>>(P2, w2, O2);
  // L3: 256->128, 8^3 -> 16^3, s2
  pad_k<8, 9, 256, 1><<<729, 256, 0, stream>>>(O2, P3);
  conv_mfma_k<64, 256, 128, 64, 1, 8, 4, 9, 1>
      <<<dim3(64, 2, 4), 256, 0, stream>>>(P3, w3, O3);
  // L4: 128->64, 16^3, s1
  pad_k<16, 18, 128, 1><<<2916, 256, 0, stream>>>(O3, P4);
  conv_mfma_k<32, 128, 64, 64, 0, 16, 4, 18, 1>
      <<<dim3(64, 1, 4), 256, 0, stream>>>(P4, w4, O4);
  // L5: 64->32, 16^3 -> 32^3, s2 -> ReLU'd fp16 directly into padded P6
  pad_k<16, 17, 64, 1><<<1229, 256, 0, stream>>>(O4, P5);
  conv_mfma_k<64, 64, 32, 32, 1, 16, 8, 17, 2>
      <<<dim3(256, 1, 1), 256, 0, stream>>>(P5, w5, P6);
  // L6: 32->1, 32^3, s1, no final ReLU
  conv6_k<<<128, 256, 0, stream>>>(P6, w6, out);

  (void)in_sizes; (void)n_in; (void)out_size; (void)ws_size;
}